// Round 13
// baseline (217.273 us; speedup 1.0000x reference)
//
#include <hip/hip_runtime.h>
#include <hip/hip_bf16.h>
#include <stdint.h>

#define FEATS 128
#define NB_MAX 512        // max buckets (supports N <= 131072)
#define CH_BLOCKS 512     // cast_hist grid (fixed; one blockHist slice each)
#define PS_B 1024         // pair-scatter block threads
#define PS_EPT 16         // edges per thread
#define PS_CHUNK (PS_B * PS_EPT)
#define GP 136            // LDS pitch in shorts (272 B rows: 16B-aligned, 2-way max conflict)

typedef short bf16x8 __attribute__((ext_vector_type(8)));
typedef float f32x4 __attribute__((ext_vector_type(4)));
typedef float f32x2 __attribute__((ext_vector_type(2)));

// ---------------- helpers ----------------

__device__ inline uint32_t f2bf(float f) {  // RTNE f32 -> bf16 (low 16 bits)
  uint32_t x = __float_as_uint(f);
  uint32_t r = ((x >> 16) & 1u) + 0x7fffu;
  return (x + r) >> 16;
}
__device__ inline float bflo(uint32_t u) { return __uint_as_float(u << 16); }
__device__ inline float bfhi(uint32_t u) { return __uint_as_float(u & 0xffff0000u); }

// ------- fused: f32->fp8 cast of X + per-block bucket histogram (no global atomics, no memset) -------

__global__ __launch_bounds__(256) void cast_hist_kernel(const float* __restrict__ X,
                                                        uint32_t* __restrict__ Xq, int nq,
                                                        const int* __restrict__ dst,
                                                        int* __restrict__ blockHist, int E) {
  __shared__ int lh[NB_MAX];
  int t = threadIdx.x;
  for (int i = t; i < NB_MAX; i += 256) lh[i] = 0;
  __syncthreads();
  int tid = blockIdx.x * blockDim.x + t;
  int stride = gridDim.x * blockDim.x;
  for (int i = tid; i < nq; i += stride) {  // nq = N*32 (4 feats per u32)
    float4 v = ((const float4*)X)[i];
    uint32_t q = __builtin_amdgcn_cvt_pk_fp8_f32(v.x, v.y, 0, false);
    q = __builtin_amdgcn_cvt_pk_fp8_f32(v.z, v.w, q, true);
    Xq[i] = q;
  }
  for (int i = tid; i < E; i += stride) atomicAdd(&lh[dst[i] >> 8], 1);
  __syncthreads();
  int* bh = blockHist + blockIdx.x * NB_MAX;
  for (int b = t; b < NB_MAX; b += 256) bh[b] = lh[b];  // unconditional store, no pre-zero needed
}

// ---- bucket scan: sum per-block hists (coalesced) + exclusive scan of bucket totals ----

__global__ __launch_bounds__(NB_MAX) void bucket_scan_kernel(const int* __restrict__ blockHist,
                                                             int* __restrict__ bucketBase,
                                                             int* __restrict__ bucketCursor, int NB) {
  __shared__ int s[NB_MAX];
  int t = threadIdx.x;
  int v = 0;
#pragma unroll 8
  for (int b = 0; b < CH_BLOCKS; ++b) v += blockHist[b * NB_MAX + t];
  s[t] = v;
  __syncthreads();
  for (int o = 1; o < NB_MAX; o <<= 1) {
    int add = (t >= o) ? s[t - o] : 0;
    __syncthreads();
    s[t] += add;
    __syncthreads();
  }
  if (t < NB) {
    int ex = s[t] - v;
    bucketBase[t] = ex;
    bucketCursor[t] = ex;
    if (t == NB - 1) bucketBase[NB] = s[t];  // = E
  }
}

// ---- pass 2: multisplit packed (src<<8 | dst&255) into dst-page buckets ----
__global__ __launch_bounds__(PS_B) void pairscatter_kernel(const int* __restrict__ src,
                                                           const int* __restrict__ dst,
                                                           int* __restrict__ bucketCursor,
                                                           uint32_t* __restrict__ pairs, int E) {
  __shared__ int hist[NB_MAX];
  __shared__ int rank[NB_MAX];
  __shared__ int res[NB_MAX];
  int t = threadIdx.x;
  int base = blockIdx.x * PS_CHUNK;

  if (t < NB_MAX) {
    hist[t] = 0;
    rank[t] = 0;
  }
  __syncthreads();

  int sr[PS_EPT], dr[PS_EPT];
#pragma unroll
  for (int j = 0; j < PS_EPT; ++j) {
    int i = base + j * PS_B + t;
    if (i < E) {
      sr[j] = src[i];
      dr[j] = dst[i];
      atomicAdd(&hist[dr[j] >> 8], 1);
    } else {
      dr[j] = -1;
    }
  }
  __syncthreads();

  if (t < NB_MAX) {
    int h = hist[t];
    res[t] = h ? atomicAdd(&bucketCursor[t], h) : 0;
  }
  __syncthreads();

#pragma unroll
  for (int j = 0; j < PS_EPT; ++j) {
    if (dr[j] >= 0) {
      int b = dr[j] >> 8;
      int r = atomicAdd(&rank[b], 1);
      pairs[(size_t)(res[b] + r)] = ((uint32_t)sr[j] << 8) | ((uint32_t)dr[j] & 255u);
    }
  }
}

// ---- fused final: per-bucket degree count (LDS) + scan (LDS) + offdeg write + scatter ----
__global__ __launch_bounds__(256) void fused_final_kernel(const uint32_t* __restrict__ pairs,
                                                          const int* __restrict__ bucketBase,
                                                          int2* __restrict__ offdeg,
                                                          int* __restrict__ srcSorted, int N) {
  __shared__ int cnt[256];
  __shared__ int scn[256];
  __shared__ int cur[256];
  int b = blockIdx.x, t = threadIdx.x;
  int bs = bucketBase[b], be = bucketBase[b + 1];
  cnt[t] = 0;
  __syncthreads();
  for (int i = bs + t; i < be; i += 256) atomicAdd(&cnt[pairs[i] & 255u], 1);
  __syncthreads();
  int v = cnt[t];
  scn[t] = v;
  __syncthreads();
  for (int o = 1; o < 256; o <<= 1) {
    int add = (t >= o) ? scn[t - o] : 0;
    __syncthreads();
    scn[t] += add;
    __syncthreads();
  }
  int myoff = bs + scn[t] - v;
  int node = b * 256 + t;
  if (node < N) offdeg[node] = make_int2(myoff, v);
  cur[t] = myoff;
  __syncthreads();
  for (int i = bs + t; i < be; i += 256) {
    uint32_t p = pairs[i];
    int pos = atomicAdd(&cur[p & 255u], 1);
    srcSorted[pos] = (int)(p >> 8);
  }
}

// ---------------- W [K=128][N=128] f32 -> Wt [n][k] bf16 packed (2 matrices, 2 blocks) ----------------

__global__ void wtrans_kernel(const float* __restrict__ W1, const float* __restrict__ W2,
                              uint32_t* __restrict__ Wt1, uint32_t* __restrict__ Wt2) {
  __shared__ uint16_t s[128 * 129];
  const float* W = blockIdx.x ? W2 : W1;
  uint32_t* Wt = blockIdx.x ? Wt2 : Wt1;
  int t = threadIdx.x;
  for (int i = t; i < 16384; i += 256) {
    int k = i >> 7, n = i & 127;
    s[n * 129 + k] = (uint16_t)f2bf(W[i]);
  }
  __syncthreads();
  for (int i = t; i < 8192; i += 256) {
    int n = i >> 6, kd = i & 63;
    uint32_t lo = s[n * 129 + kd * 2];
    uint32_t hi = s[n * 129 + kd * 2 + 1];
    Wt[i] = lo | (hi << 16);
  }
}

// ---------------- fused layer: agg (LDS) -> (x + A) @ Wt^T + bias ----------------
// 512 threads, 128-row tile. Phase A: 32 16-lane groups aggregate 128 nodes -> bf16 in LS.
// Phase B: A-fragments from LS + x from global -> registers. Phase C: restage W into LS.
// Phase D: 32 MFMAs + epilogue. Ah never touches global memory.
// LAYER=1: x = f32 X; writes bf16 Hh + fp8 Hq (LDS transpose), RELU.
// LAYER=2: x = bf16 Hh; writes f32 d_out directly.

template <int LAYER>
__global__ __launch_bounds__(512) void fused_layer(const uint32_t* __restrict__ Gq,
                                                   const float* __restrict__ Xf,
                                                   const uint32_t* __restrict__ Xb,
                                                   const int* __restrict__ srcSorted,
                                                   const int2* __restrict__ offdeg,
                                                   const uint32_t* __restrict__ Wt,
                                                   const float* __restrict__ bias,
                                                   float* __restrict__ outF,
                                                   uint32_t* __restrict__ outH,
                                                   uint8_t* __restrict__ outQ, int N) {
  __shared__ short LS[128 * GP];
  int t = threadIdx.x;
  int vbase = blockIdx.x * 128;
  int grp = t >> 4, lc = t & 15;
  const uint32_t* Xc = Gq + lc * 2;

  // ---- phase A: aggregate this tile's 128 nodes ----
#pragma unroll
  for (int r = 0; r < 4; ++r) {
    int v = vbase + r * 32 + grp;
    f32x2 a0 = {0.f, 0.f}, a1 = {0.f, 0.f}, a2 = {0.f, 0.f}, a3 = {0.f, 0.f};
    float scale = 0.f;
    if (v < N) {
      int2 od = offdeg[v];
      const int* idxp = srcSorted + od.x;
      int d = od.y;
      int e = 0;
      for (; e + 4 <= d; e += 4) {  // 4 independent gathers in flight per group
        int i0 = idxp[e];
        int i1 = idxp[e + 1];
        int i2 = idxp[e + 2];
        int i3 = idxp[e + 3];
        uint2 ua = *(const uint2*)(Xc + ((size_t)i0 << 5));
        uint2 ub = *(const uint2*)(Xc + ((size_t)i1 << 5));
        uint2 uc = *(const uint2*)(Xc + ((size_t)i2 << 5));
        uint2 ud = *(const uint2*)(Xc + ((size_t)i3 << 5));
        a0 += __builtin_amdgcn_cvt_pk_f32_fp8(ua.x, false);
        a1 += __builtin_amdgcn_cvt_pk_f32_fp8(ua.x, true);
        a2 += __builtin_amdgcn_cvt_pk_f32_fp8(ua.y, false);
        a3 += __builtin_amdgcn_cvt_pk_f32_fp8(ua.y, true);
        a0 += __builtin_amdgcn_cvt_pk_f32_fp8(ub.x, false);
        a1 += __builtin_amdgcn_cvt_pk_f32_fp8(ub.x, true);
        a2 += __builtin_amdgcn_cvt_pk_f32_fp8(ub.y, false);
        a3 += __builtin_amdgcn_cvt_pk_f32_fp8(ub.y, true);
        a0 += __builtin_amdgcn_cvt_pk_f32_fp8(uc.x, false);
        a1 += __builtin_amdgcn_cvt_pk_f32_fp8(uc.x, true);
        a2 += __builtin_amdgcn_cvt_pk_f32_fp8(uc.y, false);
        a3 += __builtin_amdgcn_cvt_pk_f32_fp8(uc.y, true);
        a0 += __builtin_amdgcn_cvt_pk_f32_fp8(ud.x, false);
        a1 += __builtin_amdgcn_cvt_pk_f32_fp8(ud.x, true);
        a2 += __builtin_amdgcn_cvt_pk_f32_fp8(ud.y, false);
        a3 += __builtin_amdgcn_cvt_pk_f32_fp8(ud.y, true);
      }
      for (; e < d; ++e) {  // tail 0..3 edges
        int i0 = idxp[e];
        uint2 ua = *(const uint2*)(Xc + ((size_t)i0 << 5));
        a0 += __builtin_amdgcn_cvt_pk_f32_fp8(ua.x, false);
        a1 += __builtin_amdgcn_cvt_pk_f32_fp8(ua.x, true);
        a2 += __builtin_amdgcn_cvt_pk_f32_fp8(ua.y, false);
        a3 += __builtin_amdgcn_cvt_pk_f32_fp8(ua.y, true);
      }
      scale = (d > 0) ? (1.0f / (float)d) : 0.0f;
    }
    uint4 o;
    o.x = f2bf(a0.x * scale) | (f2bf(a0.y * scale) << 16);
    o.y = f2bf(a1.x * scale) | (f2bf(a1.y * scale) << 16);
    o.z = f2bf(a2.x * scale) | (f2bf(a2.y * scale) << 16);
    o.w = f2bf(a3.x * scale) | (f2bf(a3.y * scale) << 16);
    *(uint4*)&LS[(r * 32 + grp) * GP + lc * 8] = o;
  }
  __syncthreads();

  // ---- phase B: build af[4] = bf16(x + A), A from LS, x from global ----
  int wave = t >> 6, l = t & 63;
  int wr = wave * 16;
  int lr = l & 15, hi = l >> 4;
  int grow = vbase + wr + lr;
  int arow = (grow < N) ? grow : (N - 1);  // clamp: garbage only corrupts OOB rows
  int lrow = wr + lr;

  uint4 af[4];
#pragma unroll
  for (int ks = 0; ks < 4; ++ks) {
    int k0 = ks * 32 + hi * 8;
    uint4 au = *(const uint4*)&LS[lrow * GP + k0];
    if (LAYER == 1) {
      float4 x0 = *(const float4*)&Xf[(size_t)arow * FEATS + k0];
      float4 x1 = *(const float4*)&Xf[(size_t)arow * FEATS + k0 + 4];
      af[ks].x = f2bf(x0.x + bflo(au.x)) | (f2bf(x0.y + bfhi(au.x)) << 16);
      af[ks].y = f2bf(x0.z + bflo(au.y)) | (f2bf(x0.w + bfhi(au.y)) << 16);
      af[ks].z = f2bf(x1.x + bflo(au.z)) | (f2bf(x1.y + bfhi(au.z)) << 16);
      af[ks].w = f2bf(x1.z + bflo(au.w)) | (f2bf(x1.w + bfhi(au.w)) << 16);
    } else {
      uint4 xu = *(const uint4*)&Xb[(size_t)arow * 64 + (k0 >> 1)];
      af[ks].x = f2bf(bflo(xu.x) + bflo(au.x)) | (f2bf(bfhi(xu.x) + bfhi(au.x)) << 16);
      af[ks].y = f2bf(bflo(xu.y) + bflo(au.y)) | (f2bf(bfhi(xu.y) + bfhi(au.y)) << 16);
      af[ks].z = f2bf(bflo(xu.z) + bflo(au.z)) | (f2bf(bfhi(xu.z) + bfhi(au.z)) << 16);
      af[ks].w = f2bf(bflo(xu.w) + bflo(au.w)) | (f2bf(bfhi(xu.w) + bfhi(au.w)) << 16);
    }
  }
  __syncthreads();  // all A reads done; LS reusable

  // ---- phase C: stage Wt into LS ----
  for (int c = t; c < 2048; c += 512) {
    int row = c >> 4, col8 = (c & 15) * 8;
    uint4 w = *(const uint4*)&Wt[row * 64 + (col8 >> 1)];
    *(uint4*)&LS[row * GP + col8] = w;
  }
  __syncthreads();

  // ---- phase D: MFMA + epilogue ----
  f32x4 acc[8];
#pragma unroll
  for (int i = 0; i < 8; ++i) acc[i] = (f32x4){0.f, 0.f, 0.f, 0.f};

#pragma unroll
  for (int ks = 0; ks < 4; ++ks) {
    bf16x8 a = *(const bf16x8*)&af[ks];
    int k0 = ks * 32 + hi * 8;
#pragma unroll
    for (int nf = 0; nf < 8; ++nf) {
      bf16x8 b = *(const bf16x8*)&LS[(nf * 16 + lr) * GP + k0];
      acc[nf] = __builtin_amdgcn_mfma_f32_16x16x32_bf16(a, b, acc[nf], 0, 0, 0);
    }
  }

  int orow = wr + hi * 4;
  if (LAYER == 1) {
    __syncthreads();  // W consumed; reuse LS for output transpose
#pragma unroll
    for (int nf = 0; nf < 8; ++nf) {
      int col = nf * 16 + lr;
      float bv = bias[col];
#pragma unroll
      for (int j = 0; j < 4; ++j) {
        float o = fmaxf(acc[nf][j] + bv, 0.f);
        ((uint16_t*)LS)[(orow + j) * GP + col] = (uint16_t)f2bf(o);
      }
    }
    __syncthreads();
    // coalesced write-out: 128 rows x 128 bf16 -> Hh (uint4) + fp8 -> Hq (uint2)
    for (int i = t; i < 2048; i += 512) {
      int row = i >> 4, c8 = (i & 15) * 8;
      int v = vbase + row;
      if (v < N) {
        uint4 hv = *(const uint4*)&LS[row * GP + c8];
        *(uint4*)((uint16_t*)outH + (size_t)v * FEATS + c8) = hv;
        uint32_t q0 = __builtin_amdgcn_cvt_pk_fp8_f32(bflo(hv.x), bfhi(hv.x), 0, false);
        q0 = __builtin_amdgcn_cvt_pk_fp8_f32(bflo(hv.y), bfhi(hv.y), q0, true);
        uint32_t q1 = __builtin_amdgcn_cvt_pk_fp8_f32(bflo(hv.z), bfhi(hv.z), 0, false);
        q1 = __builtin_amdgcn_cvt_pk_fp8_f32(bflo(hv.w), bfhi(hv.w), q1, true);
        *(uint2*)(outQ + (size_t)v * FEATS + c8) = make_uint2(q0, q1);
      }
    }
  } else {
#pragma unroll
    for (int nf = 0; nf < 8; ++nf) {
      int col = nf * 16 + lr;
      float bv = bias[col];
#pragma unroll
      for (int j = 0; j < 4; ++j) {
        int v = vbase + orow + j;
        if (v < N) outF[(size_t)v * FEATS + col] = acc[nf][j] + bv;
      }
    }
  }
}

// ---------------- launcher ----------------

extern "C" void kernel_launch(void* const* d_in, const int* in_sizes, int n_in,
                              void* d_out, int out_size, void* d_ws, size_t ws_size,
                              hipStream_t stream) {
  const float* X = (const float*)d_in[0];
  const int* src = (const int*)d_in[1];
  const int* dst = (const int*)d_in[2];
  const float* W1 = (const float*)d_in[3];
  const float* b1 = (const float*)d_in[4];
  const float* W2 = (const float*)d_in[5];
  const float* b2 = (const float*)d_in[6];
  float* out = (float*)d_out;

  int N = in_sizes[0] / FEATS;
  int E = in_sizes[1];
  int NB = (N + 255) / 256;  // dst-page buckets

  char* ws = (char*)d_ws;
  auto alloc = [&](size_t bytes) -> char* {
    char* p = ws;
    ws += (bytes + 255) & ~(size_t)255;
    return p;
  };
  int2* offdeg = (int2*)alloc((size_t)N * 8);
  int* blockHist = (int*)alloc((size_t)CH_BLOCKS * NB_MAX * 4);  // per-block hists (no memset needed)
  int* bucketBase = (int*)alloc((size_t)(NB_MAX + 1) * 4);
  int* bucketCursor = (int*)alloc((size_t)NB_MAX * 4);
  uint32_t* pairs = (uint32_t*)alloc((size_t)E * 4);
  int* srcSorted = (int*)alloc((size_t)E * 4);
  uint32_t* Xq = (uint32_t*)alloc((size_t)N * 32 * 4);  // fp8 X
  uint32_t* Hq = (uint32_t*)alloc((size_t)N * 32 * 4);  // fp8 h1 (separate: fused kernel would race an alias)
  uint32_t* Hh = (uint32_t*)alloc((size_t)N * 64 * 4);  // bf16 h1
  uint32_t* Wt1 = (uint32_t*)alloc((size_t)64 * 128 * 4);
  uint32_t* Wt2 = (uint32_t*)alloc((size_t)64 * 128 * 4);

  // ---- fused fp8 cast + per-block bucket histogram (no memset in graph) ----
  int nq = N * 32;
  cast_hist_kernel<<<CH_BLOCKS, 256, 0, stream>>>(X, Xq, nq, dst, blockHist, E);

  // ---- CSR build (no global per-node atomics anywhere) ----
  bucket_scan_kernel<<<1, NB_MAX, 0, stream>>>(blockHist, bucketBase, bucketCursor, NB);
  pairscatter_kernel<<<(E + PS_CHUNK - 1) / PS_CHUNK, PS_B, 0, stream>>>(src, dst, bucketCursor,
                                                                         pairs, E);
  fused_final_kernel<<<NB, 256, 0, stream>>>(pairs, bucketBase, offdeg, srcSorted, N);

  // ---- weight transpose ----
  wtrans_kernel<<<2, 256, 0, stream>>>(W1, W2, Wt1, Wt2);

  int gb = (N + 127) / 128;

  // ---- layer 1: fused agg(Xq) + relu((X+A)@W1+b1) -> Hh (bf16) + Hq (fp8) ----
  fused_layer<1><<<gb, 512, 0, stream>>>(Xq, X, nullptr, srcSorted, offdeg, Wt1, b1,
                                         nullptr, Hh, (uint8_t*)Hq, N);

  // ---- layer 2: fused agg(Hq) + (Hh+A)@W2+b2 -> f32 d_out ----
  fused_layer<2><<<gb, 512, 0, stream>>>(Hq, nullptr, Hh, srcSorted, offdeg, Wt2, b2,
                                         out, nullptr, nullptr, N);
}

// Round 14
// 185.484 us; speedup vs baseline: 1.1714x; 1.1714x over previous
//
#include <hip/hip_runtime.h>
#include <hip/hip_bf16.h>
#include <stdint.h>

#define FEATS 128
#define NB_MAX 512        // max buckets (supports N <= 131072)
#define CH_BLOCKS 512     // cast_hist grid (fixed; one blockHist slice each)
#define PS_B 1024         // pair-scatter block threads
#define PS_EPT 16         // edges per thread
#define PS_CHUNK (PS_B * PS_EPT)
#define GP 136            // GEMM LDS pitch in shorts (272 B rows: 16B-aligned, 2-way max conflict)

typedef short bf16x8 __attribute__((ext_vector_type(8)));
typedef float f32x4 __attribute__((ext_vector_type(4)));
typedef float f32x2 __attribute__((ext_vector_type(2)));

// ---------------- helpers ----------------

__device__ inline uint32_t f2bf(float f) {  // RTNE f32 -> bf16 (low 16 bits)
  uint32_t x = __float_as_uint(f);
  uint32_t r = ((x >> 16) & 1u) + 0x7fffu;
  return (x + r) >> 16;
}
__device__ inline float bflo(uint32_t u) { return __uint_as_float(u << 16); }
__device__ inline float bfhi(uint32_t u) { return __uint_as_float(u & 0xffff0000u); }

// ------- fused: f32->fp8 cast of X + per-block bucket histogram (no global atomics, no memset) -------

__global__ __launch_bounds__(256) void cast_hist_kernel(const float* __restrict__ X,
                                                        uint32_t* __restrict__ Xq, int nq,
                                                        const int* __restrict__ dst,
                                                        int* __restrict__ blockHist, int E) {
  __shared__ int lh[NB_MAX];
  int t = threadIdx.x;
  for (int i = t; i < NB_MAX; i += 256) lh[i] = 0;
  __syncthreads();
  int tid = blockIdx.x * blockDim.x + t;
  int stride = gridDim.x * blockDim.x;
  for (int i = tid; i < nq; i += stride) {  // nq = N*32 (4 feats per u32)
    float4 v = ((const float4*)X)[i];
    uint32_t q = __builtin_amdgcn_cvt_pk_fp8_f32(v.x, v.y, 0, false);
    q = __builtin_amdgcn_cvt_pk_fp8_f32(v.z, v.w, q, true);
    Xq[i] = q;
  }
  for (int i = tid; i < E; i += stride) atomicAdd(&lh[dst[i] >> 8], 1);
  __syncthreads();
  int* bh = blockHist + blockIdx.x * NB_MAX;
  for (int b = t; b < NB_MAX; b += 256) bh[b] = lh[b];  // unconditional store, no pre-zero needed
}

// ---- bucket scan: sum per-block hists (coalesced) + exclusive scan of bucket totals ----

__global__ __launch_bounds__(NB_MAX) void bucket_scan_kernel(const int* __restrict__ blockHist,
                                                             int* __restrict__ bucketBase,
                                                             int* __restrict__ bucketCursor, int NB) {
  __shared__ int s[NB_MAX];
  int t = threadIdx.x;
  int v = 0;
#pragma unroll 8
  for (int b = 0; b < CH_BLOCKS; ++b) v += blockHist[b * NB_MAX + t];
  s[t] = v;
  __syncthreads();
  for (int o = 1; o < NB_MAX; o <<= 1) {
    int add = (t >= o) ? s[t - o] : 0;
    __syncthreads();
    s[t] += add;
    __syncthreads();
  }
  if (t < NB) {
    int ex = s[t] - v;
    bucketBase[t] = ex;
    bucketCursor[t] = ex;
    if (t == NB - 1) bucketBase[NB] = s[t];  // = E
  }
}

// ---- pass 2: multisplit packed (src<<8 | dst&255) into dst-page buckets ----
__global__ __launch_bounds__(PS_B) void pairscatter_kernel(const int* __restrict__ src,
                                                           const int* __restrict__ dst,
                                                           int* __restrict__ bucketCursor,
                                                           uint32_t* __restrict__ pairs, int E) {
  __shared__ int hist[NB_MAX];
  __shared__ int rank[NB_MAX];
  __shared__ int res[NB_MAX];
  int t = threadIdx.x;
  int base = blockIdx.x * PS_CHUNK;

  if (t < NB_MAX) {
    hist[t] = 0;
    rank[t] = 0;
  }
  __syncthreads();

  int sr[PS_EPT], dr[PS_EPT];
#pragma unroll
  for (int j = 0; j < PS_EPT; ++j) {
    int i = base + j * PS_B + t;
    if (i < E) {
      sr[j] = src[i];
      dr[j] = dst[i];
      atomicAdd(&hist[dr[j] >> 8], 1);
    } else {
      dr[j] = -1;
    }
  }
  __syncthreads();

  if (t < NB_MAX) {
    int h = hist[t];
    res[t] = h ? atomicAdd(&bucketCursor[t], h) : 0;
  }
  __syncthreads();

#pragma unroll
  for (int j = 0; j < PS_EPT; ++j) {
    if (dr[j] >= 0) {
      int b = dr[j] >> 8;
      int r = atomicAdd(&rank[b], 1);
      pairs[(size_t)(res[b] + r)] = ((uint32_t)sr[j] << 8) | ((uint32_t)dr[j] & 255u);
    }
  }
}

// ---- fused final: per-bucket degree count (LDS) + scan (LDS) + offdeg write + scatter ----
__global__ __launch_bounds__(256) void fused_final_kernel(const uint32_t* __restrict__ pairs,
                                                          const int* __restrict__ bucketBase,
                                                          int2* __restrict__ offdeg,
                                                          int* __restrict__ srcSorted, int N) {
  __shared__ int cnt[256];
  __shared__ int scn[256];
  __shared__ int cur[256];
  int b = blockIdx.x, t = threadIdx.x;
  int bs = bucketBase[b], be = bucketBase[b + 1];
  cnt[t] = 0;
  __syncthreads();
  for (int i = bs + t; i < be; i += 256) atomicAdd(&cnt[pairs[i] & 255u], 1);
  __syncthreads();
  int v = cnt[t];
  scn[t] = v;
  __syncthreads();
  for (int o = 1; o < 256; o <<= 1) {
    int add = (t >= o) ? scn[t - o] : 0;
    __syncthreads();
    scn[t] += add;
    __syncthreads();
  }
  int myoff = bs + scn[t] - v;
  int node = b * 256 + t;
  if (node < N) offdeg[node] = make_int2(myoff, v);
  cur[t] = myoff;
  __syncthreads();
  for (int i = bs + t; i < be; i += 256) {
    uint32_t p = pairs[i];
    int pos = atomicAdd(&cur[p & 255u], 1);
    srcSorted[pos] = (int)(p >> 8);
  }
}

// ---------------- W [K=128][N=128] f32 -> Wt [n][k] bf16 packed (2 matrices, 2 blocks) ----------------

__global__ void wtrans_kernel(const float* __restrict__ W1, const float* __restrict__ W2,
                              uint32_t* __restrict__ Wt1, uint32_t* __restrict__ Wt2) {
  __shared__ uint16_t s[128 * 129];
  const float* W = blockIdx.x ? W2 : W1;
  uint32_t* Wt = blockIdx.x ? Wt2 : Wt1;
  int t = threadIdx.x;
  for (int i = t; i < 16384; i += 256) {
    int k = i >> 7, n = i & 127;
    s[n * 129 + k] = (uint16_t)f2bf(W[i]);
  }
  __syncthreads();
  for (int i = t; i < 8192; i += 256) {
    int n = i >> 6, kd = i & 63;
    uint32_t lo = s[n * 129 + kd * 2];
    uint32_t hi = s[n * 129 + kd * 2 + 1];
    Wt[i] = lo | (hi << 16);
  }
}

// ---- mean aggregation: 16 lanes per node (4 nodes/wave); 8x edge unroll -> 32 gathers in flight/wave ----

__global__ void agg_kernel(const uint32_t* __restrict__ Xq, const int* __restrict__ srcSorted,
                           const int2* __restrict__ offdeg, uint32_t* __restrict__ Ah, int N) {
  int t = threadIdx.x;
  int v = blockIdx.x * 16 + (t >> 4);  // node for this 16-lane group
  int lc = t & 15;                     // 8-feat column group; u32 offset lc*2 within 32-u32 row
  if (v >= N) return;
  int2 od = offdeg[v];
  int start = od.x, d = od.y;
  const int* idxp = srcSorted + start;
  const uint32_t* Xc = Xq + lc * 2;

  f32x2 a0 = {0.f, 0.f}, a1 = {0.f, 0.f}, a2 = {0.f, 0.f}, a3 = {0.f, 0.f};

  int e = 0;
  for (; e + 8 <= d; e += 8) {  // 8 independent gathers in flight per group (32/wave)
    int i0 = idxp[e];
    int i1 = idxp[e + 1];
    int i2 = idxp[e + 2];
    int i3 = idxp[e + 3];
    int i4 = idxp[e + 4];
    int i5 = idxp[e + 5];
    int i6 = idxp[e + 6];
    int i7 = idxp[e + 7];
    uint2 ua = *(const uint2*)(Xc + ((size_t)i0 << 5));
    uint2 ub = *(const uint2*)(Xc + ((size_t)i1 << 5));
    uint2 uc = *(const uint2*)(Xc + ((size_t)i2 << 5));
    uint2 ud = *(const uint2*)(Xc + ((size_t)i3 << 5));
    uint2 ue = *(const uint2*)(Xc + ((size_t)i4 << 5));
    uint2 uf = *(const uint2*)(Xc + ((size_t)i5 << 5));
    uint2 ug = *(const uint2*)(Xc + ((size_t)i6 << 5));
    uint2 uh = *(const uint2*)(Xc + ((size_t)i7 << 5));
    a0 += __builtin_amdgcn_cvt_pk_f32_fp8(ua.x, false);
    a1 += __builtin_amdgcn_cvt_pk_f32_fp8(ua.x, true);
    a2 += __builtin_amdgcn_cvt_pk_f32_fp8(ua.y, false);
    a3 += __builtin_amdgcn_cvt_pk_f32_fp8(ua.y, true);
    a0 += __builtin_amdgcn_cvt_pk_f32_fp8(ub.x, false);
    a1 += __builtin_amdgcn_cvt_pk_f32_fp8(ub.x, true);
    a2 += __builtin_amdgcn_cvt_pk_f32_fp8(ub.y, false);
    a3 += __builtin_amdgcn_cvt_pk_f32_fp8(ub.y, true);
    a0 += __builtin_amdgcn_cvt_pk_f32_fp8(uc.x, false);
    a1 += __builtin_amdgcn_cvt_pk_f32_fp8(uc.x, true);
    a2 += __builtin_amdgcn_cvt_pk_f32_fp8(uc.y, false);
    a3 += __builtin_amdgcn_cvt_pk_f32_fp8(uc.y, true);
    a0 += __builtin_amdgcn_cvt_pk_f32_fp8(ud.x, false);
    a1 += __builtin_amdgcn_cvt_pk_f32_fp8(ud.x, true);
    a2 += __builtin_amdgcn_cvt_pk_f32_fp8(ud.y, false);
    a3 += __builtin_amdgcn_cvt_pk_f32_fp8(ud.y, true);
    a0 += __builtin_amdgcn_cvt_pk_f32_fp8(ue.x, false);
    a1 += __builtin_amdgcn_cvt_pk_f32_fp8(ue.x, true);
    a2 += __builtin_amdgcn_cvt_pk_f32_fp8(ue.y, false);
    a3 += __builtin_amdgcn_cvt_pk_f32_fp8(ue.y, true);
    a0 += __builtin_amdgcn_cvt_pk_f32_fp8(uf.x, false);
    a1 += __builtin_amdgcn_cvt_pk_f32_fp8(uf.x, true);
    a2 += __builtin_amdgcn_cvt_pk_f32_fp8(uf.y, false);
    a3 += __builtin_amdgcn_cvt_pk_f32_fp8(uf.y, true);
    a0 += __builtin_amdgcn_cvt_pk_f32_fp8(ug.x, false);
    a1 += __builtin_amdgcn_cvt_pk_f32_fp8(ug.x, true);
    a2 += __builtin_amdgcn_cvt_pk_f32_fp8(ug.y, false);
    a3 += __builtin_amdgcn_cvt_pk_f32_fp8(ug.y, true);
    a0 += __builtin_amdgcn_cvt_pk_f32_fp8(uh.x, false);
    a1 += __builtin_amdgcn_cvt_pk_f32_fp8(uh.x, true);
    a2 += __builtin_amdgcn_cvt_pk_f32_fp8(uh.y, false);
    a3 += __builtin_amdgcn_cvt_pk_f32_fp8(uh.y, true);
  }
  if (e + 4 <= d) {
    int i0 = idxp[e];
    int i1 = idxp[e + 1];
    int i2 = idxp[e + 2];
    int i3 = idxp[e + 3];
    uint2 ua = *(const uint2*)(Xc + ((size_t)i0 << 5));
    uint2 ub = *(const uint2*)(Xc + ((size_t)i1 << 5));
    uint2 uc = *(const uint2*)(Xc + ((size_t)i2 << 5));
    uint2 ud = *(const uint2*)(Xc + ((size_t)i3 << 5));
    a0 += __builtin_amdgcn_cvt_pk_f32_fp8(ua.x, false);
    a1 += __builtin_amdgcn_cvt_pk_f32_fp8(ua.x, true);
    a2 += __builtin_amdgcn_cvt_pk_f32_fp8(ua.y, false);
    a3 += __builtin_amdgcn_cvt_pk_f32_fp8(ua.y, true);
    a0 += __builtin_amdgcn_cvt_pk_f32_fp8(ub.x, false);
    a1 += __builtin_amdgcn_cvt_pk_f32_fp8(ub.x, true);
    a2 += __builtin_amdgcn_cvt_pk_f32_fp8(ub.y, false);
    a3 += __builtin_amdgcn_cvt_pk_f32_fp8(ub.y, true);
    a0 += __builtin_amdgcn_cvt_pk_f32_fp8(uc.x, false);
    a1 += __builtin_amdgcn_cvt_pk_f32_fp8(uc.x, true);
    a2 += __builtin_amdgcn_cvt_pk_f32_fp8(uc.y, false);
    a3 += __builtin_amdgcn_cvt_pk_f32_fp8(uc.y, true);
    a0 += __builtin_amdgcn_cvt_pk_f32_fp8(ud.x, false);
    a1 += __builtin_amdgcn_cvt_pk_f32_fp8(ud.x, true);
    a2 += __builtin_amdgcn_cvt_pk_f32_fp8(ud.y, false);
    a3 += __builtin_amdgcn_cvt_pk_f32_fp8(ud.y, true);
    e += 4;
  }
  for (; e < d; ++e) {  // tail 0..3 edges
    int i0 = idxp[e];
    uint2 ua = *(const uint2*)(Xc + ((size_t)i0 << 5));
    a0 += __builtin_amdgcn_cvt_pk_f32_fp8(ua.x, false);
    a1 += __builtin_amdgcn_cvt_pk_f32_fp8(ua.x, true);
    a2 += __builtin_amdgcn_cvt_pk_f32_fp8(ua.y, false);
    a3 += __builtin_amdgcn_cvt_pk_f32_fp8(ua.y, true);
  }

  float scale = (d > 0) ? (1.0f / (float)d) : 0.0f;
  uint4 o;
  o.x = f2bf(a0.x * scale) | (f2bf(a0.y * scale) << 16);
  o.y = f2bf(a1.x * scale) | (f2bf(a1.y * scale) << 16);
  o.z = f2bf(a2.x * scale) | (f2bf(a2.y * scale) << 16);
  o.w = f2bf(a3.x * scale) | (f2bf(a3.y * scale) << 16);
  *(uint4*)&Ah[(size_t)v * 64 + lc * 4] = o;
}

// ---------------- MFMA GEMM: out = (x + A) @ Wt^T + bias ----------------
// 512 threads, 128-row tile. W staged ONCE in LDS (only LDS use); A-fragments built
// directly from global per lane. LAYER=1: x f32 X -> transpose epilogue via WS (reused),
// bf16 Hh + fp8 Hq, RELU. LAYER=2: x bf16 Hh -> direct f32 stores.

template <int LAYER>
__global__ __launch_bounds__(512) void gemm_mfma(const float* __restrict__ Xf,
                                                 const uint32_t* __restrict__ Xb,
                                                 const uint32_t* __restrict__ Ab,
                                                 const uint32_t* __restrict__ Wt,
                                                 const float* __restrict__ bias,
                                                 float* __restrict__ outF,
                                                 uint32_t* __restrict__ outH,
                                                 uint8_t* __restrict__ outQ, int N) {
  __shared__ short WS[128 * GP];
  int t = threadIdx.x;
  int vbase = blockIdx.x * 128;

  // stage Wt (16B chunks): 2048 chunks of 8 shorts
  for (int c = t; c < 2048; c += 512) {
    int row = c >> 4, col8 = (c & 15) * 8;
    uint4 w = *(const uint4*)&Wt[row * 64 + (col8 >> 1)];
    *(uint4*)&WS[row * GP + col8] = w;
  }

  int wave = t >> 6, l = t & 63;
  int wr = wave * 16;                    // wave's 16 output rows (0..127)
  int lr = l & 15, hi = l >> 4;
  int grow = vbase + wr + lr;            // global row whose A-fragment this lane holds
  int arow = (grow < N) ? grow : (N - 1);  // clamp: garbage only corrupts OOB rows

  // build A-fragments for all 4 ks directly from global (8 loads in flight)
  uint4 af[4];
  if (LAYER == 1) {
#pragma unroll
    for (int ks = 0; ks < 4; ++ks) {
      int k0 = ks * 32 + hi * 8;
      float4 x0 = *(const float4*)&Xf[(size_t)arow * FEATS + k0];
      float4 x1 = *(const float4*)&Xf[(size_t)arow * FEATS + k0 + 4];
      uint4 au = *(const uint4*)&Ab[(size_t)arow * 64 + (k0 >> 1)];
      af[ks].x = f2bf(x0.x + bflo(au.x)) | (f2bf(x0.y + bfhi(au.x)) << 16);
      af[ks].y = f2bf(x0.z + bflo(au.y)) | (f2bf(x0.w + bfhi(au.y)) << 16);
      af[ks].z = f2bf(x1.x + bflo(au.z)) | (f2bf(x1.y + bfhi(au.z)) << 16);
      af[ks].w = f2bf(x1.z + bflo(au.w)) | (f2bf(x1.w + bfhi(au.w)) << 16);
    }
  } else {
#pragma unroll
    for (int ks = 0; ks < 4; ++ks) {
      int k0 = ks * 32 + hi * 8;
      uint4 xu = *(const uint4*)&Xb[(size_t)arow * 64 + (k0 >> 1)];
      uint4 au = *(const uint4*)&Ab[(size_t)arow * 64 + (k0 >> 1)];
      af[ks].x = f2bf(bflo(xu.x) + bflo(au.x)) | (f2bf(bfhi(xu.x) + bfhi(au.x)) << 16);
      af[ks].y = f2bf(bflo(xu.y) + bflo(au.y)) | (f2bf(bfhi(xu.y) + bfhi(au.y)) << 16);
      af[ks].z = f2bf(bflo(xu.z) + bflo(au.z)) | (f2bf(bfhi(xu.z) + bfhi(au.z)) << 16);
      af[ks].w = f2bf(bflo(xu.w) + bflo(au.w)) | (f2bf(bfhi(xu.w) + bfhi(au.w)) << 16);
    }
  }
  __syncthreads();  // WS ready

  f32x4 acc[8];
#pragma unroll
  for (int i = 0; i < 8; ++i) acc[i] = (f32x4){0.f, 0.f, 0.f, 0.f};

#pragma unroll
  for (int ks = 0; ks < 4; ++ks) {
    bf16x8 a = *(const bf16x8*)&af[ks];
    int k0 = ks * 32 + hi * 8;
#pragma unroll
    for (int nf = 0; nf < 8; ++nf) {
      bf16x8 b = *(const bf16x8*)&WS[(nf * 16 + lr) * GP + k0];
      acc[nf] = __builtin_amdgcn_mfma_f32_16x16x32_bf16(a, b, acc[nf], 0, 0, 0);
    }
  }

  // epilogue: D col = lane&15, row = hi*4 + j (within wave's 16 rows)
  int orow = wr + hi * 4;
  if (LAYER == 1) {
    __syncthreads();  // W consumed; reuse WS for output transpose (128 x GP shorts)
#pragma unroll
    for (int nf = 0; nf < 8; ++nf) {
      int col = nf * 16 + lr;
      float bv = bias[col];
#pragma unroll
      for (int j = 0; j < 4; ++j) {
        float o = fmaxf(acc[nf][j] + bv, 0.f);
        ((uint16_t*)WS)[(orow + j) * GP + col] = (uint16_t)f2bf(o);
      }
    }
    __syncthreads();
    // coalesced write-out: 128 rows x 128 bf16 -> Hh (uint4) + fp8 -> Hq (uint2)
    for (int i = t; i < 2048; i += 512) {
      int row = i >> 4, c8 = (i & 15) * 8;
      int v = vbase + row;
      if (v < N) {
        uint4 hv = *(const uint4*)&WS[row * GP + c8];
        *(uint4*)((uint16_t*)outH + (size_t)v * FEATS + c8) = hv;
        uint32_t q0 = __builtin_amdgcn_cvt_pk_fp8_f32(bflo(hv.x), bfhi(hv.x), 0, false);
        q0 = __builtin_amdgcn_cvt_pk_fp8_f32(bflo(hv.y), bfhi(hv.y), q0, true);
        uint32_t q1 = __builtin_amdgcn_cvt_pk_fp8_f32(bflo(hv.z), bfhi(hv.z), 0, false);
        q1 = __builtin_amdgcn_cvt_pk_fp8_f32(bflo(hv.w), bfhi(hv.w), q1, true);
        *(uint2*)(outQ + (size_t)v * FEATS + c8) = make_uint2(q0, q1);
      }
    }
  } else {
#pragma unroll
    for (int nf = 0; nf < 8; ++nf) {
      int col = nf * 16 + lr;
      float bv = bias[col];
#pragma unroll
      for (int j = 0; j < 4; ++j) {
        int v = vbase + orow + j;
        if (v < N) outF[(size_t)v * FEATS + col] = acc[nf][j] + bv;
      }
    }
  }
}

// ---------------- launcher ----------------

extern "C" void kernel_launch(void* const* d_in, const int* in_sizes, int n_in,
                              void* d_out, int out_size, void* d_ws, size_t ws_size,
                              hipStream_t stream) {
  const float* X = (const float*)d_in[0];
  const int* src = (const int*)d_in[1];
  const int* dst = (const int*)d_in[2];
  const float* W1 = (const float*)d_in[3];
  const float* b1 = (const float*)d_in[4];
  const float* W2 = (const float*)d_in[5];
  const float* b2 = (const float*)d_in[6];
  float* out = (float*)d_out;

  int N = in_sizes[0] / FEATS;
  int E = in_sizes[1];
  int NB = (N + 255) / 256;  // dst-page buckets

  char* ws = (char*)d_ws;
  auto alloc = [&](size_t bytes) -> char* {
    char* p = ws;
    ws += (bytes + 255) & ~(size_t)255;
    return p;
  };
  int2* offdeg = (int2*)alloc((size_t)N * 8);
  int* blockHist = (int*)alloc((size_t)CH_BLOCKS * NB_MAX * 4);  // per-block hists (no memset needed)
  int* bucketBase = (int*)alloc((size_t)(NB_MAX + 1) * 4);
  int* bucketCursor = (int*)alloc((size_t)NB_MAX * 4);
  uint32_t* pairs = (uint32_t*)alloc((size_t)E * 4);
  int* srcSorted = (int*)alloc((size_t)E * 4);
  uint32_t* Xq = (uint32_t*)alloc((size_t)N * 32 * 4);  // fp8 X; becomes fp8 h1 after gemm1 (alias)
  uint32_t* Ah = (uint32_t*)alloc((size_t)N * 64 * 4);  // bf16 aggregate
  uint32_t* Hh = (uint32_t*)alloc((size_t)N * 64 * 4);  // bf16 h1
  uint32_t* Wt1 = (uint32_t*)alloc((size_t)64 * 128 * 4);
  uint32_t* Wt2 = (uint32_t*)alloc((size_t)64 * 128 * 4);
  uint32_t* Hq = Xq;  // safe alias: Xq fully consumed by agg1 before gemm1 writes Hq

  // ---- fused fp8 cast + per-block bucket histogram (no memset in graph) ----
  int nq = N * 32;
  cast_hist_kernel<<<CH_BLOCKS, 256, 0, stream>>>(X, Xq, nq, dst, blockHist, E);

  // ---- CSR build (no global per-node atomics anywhere) ----
  bucket_scan_kernel<<<1, NB_MAX, 0, stream>>>(blockHist, bucketBase, bucketCursor, NB);
  pairscatter_kernel<<<(E + PS_CHUNK - 1) / PS_CHUNK, PS_B, 0, stream>>>(src, dst, bucketCursor,
                                                                         pairs, E);
  fused_final_kernel<<<NB, 256, 0, stream>>>(pairs, bucketBase, offdeg, srcSorted, N);

  // ---- weight transpose ----
  wtrans_kernel<<<2, 256, 0, stream>>>(W1, W2, Wt1, Wt2);

  int aggBlocks = (N + 15) / 16;
  int gb = (N + 127) / 128;

  // ---- layer 1: Ah = agg_fp8(Xq); Hh/Hq = relu((X+Ah)@W1+b1) ----
  agg_kernel<<<aggBlocks, 256, 0, stream>>>(Xq, srcSorted, offdeg, Ah, N);
  gemm_mfma<1><<<gb, 512, 0, stream>>>(X, nullptr, Ah, Wt1, b1, nullptr, Hh, (uint8_t*)Hq, N);

  // ---- layer 2: Ah = agg_fp8(Hq); out = (Hh+Ah)@W2+b2 (f32) ----
  agg_kernel<<<aggBlocks, 256, 0, stream>>>(Hq, srcSorted, offdeg, Ah, N);
  gemm_mfma<2><<<gb, 512, 0, stream>>>(nullptr, Hh, Ah, Wt2, b2, out, nullptr, nullptr, N);
}

// Round 15
// 179.466 us; speedup vs baseline: 1.2107x; 1.0335x over previous
//
#include <hip/hip_runtime.h>
#include <hip/hip_bf16.h>
#include <stdint.h>

#define FEATS 128
#define NB_MAX 512        // max buckets (supports N <= 131072)
#define CH_BLOCKS 512     // cast_hist grid (fixed; one blockHist slice each; +2 blocks do wtrans)
#define PS_B 1024         // pair-scatter block threads
#define PS_EPT 16         // edges per thread
#define PS_CHUNK (PS_B * PS_EPT)
#define GP 136            // GEMM LDS pitch in shorts (272 B rows: 16B-aligned, 2-way max conflict)

typedef short bf16x8 __attribute__((ext_vector_type(8)));
typedef float f32x4 __attribute__((ext_vector_type(4)));
typedef float f32x2 __attribute__((ext_vector_type(2)));

// ---------------- helpers ----------------

__device__ inline uint32_t f2bf(float f) {  // RTNE f32 -> bf16 (low 16 bits)
  uint32_t x = __float_as_uint(f);
  uint32_t r = ((x >> 16) & 1u) + 0x7fffu;
  return (x + r) >> 16;
}
__device__ inline float bflo(uint32_t u) { return __uint_as_float(u << 16); }
__device__ inline float bfhi(uint32_t u) { return __uint_as_float(u & 0xffff0000u); }

// ------- fused: f32->fp8 cast of X + per-block bucket histogram + W transpose (blocks 512/513) -------

__global__ __launch_bounds__(256) void cast_hist_kernel(const float* __restrict__ X,
                                                        uint32_t* __restrict__ Xq, int nq,
                                                        const int* __restrict__ dst,
                                                        int* __restrict__ blockHist, int E,
                                                        const float* __restrict__ W1,
                                                        const float* __restrict__ W2,
                                                        uint32_t* __restrict__ Wt1,
                                                        uint32_t* __restrict__ Wt2) {
  int t = threadIdx.x;
  if (blockIdx.x >= CH_BLOCKS) {  // W transpose blocks
    __shared__ uint16_t s[128 * 129];
    const float* W = (blockIdx.x == CH_BLOCKS) ? W1 : W2;
    uint32_t* Wt = (blockIdx.x == CH_BLOCKS) ? Wt1 : Wt2;
    for (int i = t; i < 16384; i += 256) {
      int k = i >> 7, n = i & 127;
      s[n * 129 + k] = (uint16_t)f2bf(W[i]);
    }
    __syncthreads();
    for (int i = t; i < 8192; i += 256) {
      int n = i >> 6, kd = i & 63;
      uint32_t lo = s[n * 129 + kd * 2];
      uint32_t hi = s[n * 129 + kd * 2 + 1];
      Wt[i] = lo | (hi << 16);
    }
    return;
  }
  __shared__ int lh[NB_MAX];
  for (int i = t; i < NB_MAX; i += 256) lh[i] = 0;
  __syncthreads();
  int tid = blockIdx.x * blockDim.x + t;
  int stride = CH_BLOCKS * blockDim.x;
  for (int i = tid; i < nq; i += stride) {  // nq = N*32 (4 feats per u32)
    float4 v = ((const float4*)X)[i];
    uint32_t q = __builtin_amdgcn_cvt_pk_fp8_f32(v.x, v.y, 0, false);
    q = __builtin_amdgcn_cvt_pk_fp8_f32(v.z, v.w, q, true);
    Xq[i] = q;
  }
  for (int i = tid; i < E; i += stride) atomicAdd(&lh[dst[i] >> 8], 1);
  __syncthreads();
  int* bh = blockHist + blockIdx.x * NB_MAX;
  for (int b = t; b < NB_MAX; b += 256) bh[b] = lh[b];  // unconditional store, no pre-zero needed
}

// ---- bucket scan: sum per-block hists (coalesced) + exclusive scan of bucket totals ----

__global__ __launch_bounds__(NB_MAX) void bucket_scan_kernel(const int* __restrict__ blockHist,
                                                             int* __restrict__ bucketBase,
                                                             int* __restrict__ bucketCursor, int NB) {
  __shared__ int s[NB_MAX];
  int t = threadIdx.x;
  int v = 0;
#pragma unroll 8
  for (int b = 0; b < CH_BLOCKS; ++b) v += blockHist[b * NB_MAX + t];
  s[t] = v;
  __syncthreads();
  for (int o = 1; o < NB_MAX; o <<= 1) {
    int add = (t >= o) ? s[t - o] : 0;
    __syncthreads();
    s[t] += add;
    __syncthreads();
  }
  if (t < NB) {
    int ex = s[t] - v;
    bucketBase[t] = ex;
    bucketCursor[t] = ex;
    if (t == NB - 1) bucketBase[NB] = s[t];  // = E
  }
}

// ---- pass 2: multisplit packed (src<<8 | dst&255) into dst-page buckets ----
// rank-fused: the hist atomicAdd's return value IS the within-block rank (one LDS pass).
__global__ __launch_bounds__(PS_B) void pairscatter_kernel(const int* __restrict__ src,
                                                           const int* __restrict__ dst,
                                                           int* __restrict__ bucketCursor,
                                                           uint32_t* __restrict__ pairs, int E) {
  __shared__ int hist[NB_MAX];
  __shared__ int res[NB_MAX];
  int t = threadIdx.x;
  int base = blockIdx.x * PS_CHUNK;

  if (t < NB_MAX) hist[t] = 0;
  __syncthreads();

  int sr[PS_EPT], dr[PS_EPT], rk[PS_EPT];
#pragma unroll
  for (int j = 0; j < PS_EPT; ++j) {
    int i = base + j * PS_B + t;
    if (i < E) {
      sr[j] = src[i];
      dr[j] = dst[i];
      rk[j] = atomicAdd(&hist[dr[j] >> 8], 1);  // rank within block, fused with histogram
    } else {
      dr[j] = -1;
    }
  }
  __syncthreads();

  if (t < NB_MAX) {
    int h = hist[t];
    res[t] = h ? atomicAdd(&bucketCursor[t], h) : 0;
  }
  __syncthreads();

#pragma unroll
  for (int j = 0; j < PS_EPT; ++j) {
    if (dr[j] >= 0) {
      int b = dr[j] >> 8;
      pairs[(size_t)(res[b] + rk[j])] = ((uint32_t)sr[j] << 8) | ((uint32_t)dr[j] & 255u);
    }
  }
}

// ---- fused final: per-bucket degree count (LDS) + scan (LDS) + offdeg write + scatter ----
__global__ __launch_bounds__(256) void fused_final_kernel(const uint32_t* __restrict__ pairs,
                                                          const int* __restrict__ bucketBase,
                                                          int2* __restrict__ offdeg,
                                                          int* __restrict__ srcSorted, int N) {
  __shared__ int cnt[256];
  __shared__ int scn[256];
  __shared__ int cur[256];
  int b = blockIdx.x, t = threadIdx.x;
  int bs = bucketBase[b], be = bucketBase[b + 1];
  cnt[t] = 0;
  __syncthreads();
  for (int i = bs + t; i < be; i += 256) atomicAdd(&cnt[pairs[i] & 255u], 1);
  __syncthreads();
  int v = cnt[t];
  scn[t] = v;
  __syncthreads();
  for (int o = 1; o < 256; o <<= 1) {
    int add = (t >= o) ? scn[t - o] : 0;
    __syncthreads();
    scn[t] += add;
    __syncthreads();
  }
  int myoff = bs + scn[t] - v;
  int node = b * 256 + t;
  if (node < N) offdeg[node] = make_int2(myoff, v);
  cur[t] = myoff;
  __syncthreads();
  for (int i = bs + t; i < be; i += 256) {
    uint32_t p = pairs[i];
    int pos = atomicAdd(&cur[p & 255u], 1);
    srcSorted[pos] = (int)(p >> 8);
  }
}

// ---- mean aggregation: 16 lanes per node (4 nodes/wave); 8x edge unroll -> 32 gathers in flight/wave ----

__global__ void agg_kernel(const uint32_t* __restrict__ Xq, const int* __restrict__ srcSorted,
                           const int2* __restrict__ offdeg, uint32_t* __restrict__ Ah, int N) {
  int t = threadIdx.x;
  int v = blockIdx.x * 16 + (t >> 4);  // node for this 16-lane group
  int lc = t & 15;                     // 8-feat column group; u32 offset lc*2 within 32-u32 row
  if (v >= N) return;
  int2 od = offdeg[v];
  int start = od.x, d = od.y;
  const int* idxp = srcSorted + start;
  const uint32_t* Xc = Xq + lc * 2;

  f32x2 a0 = {0.f, 0.f}, a1 = {0.f, 0.f}, a2 = {0.f, 0.f}, a3 = {0.f, 0.f};

  int e = 0;
  for (; e + 8 <= d; e += 8) {  // 8 independent gathers in flight per group (32/wave)
    int i0 = idxp[e];
    int i1 = idxp[e + 1];
    int i2 = idxp[e + 2];
    int i3 = idxp[e + 3];
    int i4 = idxp[e + 4];
    int i5 = idxp[e + 5];
    int i6 = idxp[e + 6];
    int i7 = idxp[e + 7];
    uint2 ua = *(const uint2*)(Xc + ((size_t)i0 << 5));
    uint2 ub = *(const uint2*)(Xc + ((size_t)i1 << 5));
    uint2 uc = *(const uint2*)(Xc + ((size_t)i2 << 5));
    uint2 ud = *(const uint2*)(Xc + ((size_t)i3 << 5));
    uint2 ue = *(const uint2*)(Xc + ((size_t)i4 << 5));
    uint2 uf = *(const uint2*)(Xc + ((size_t)i5 << 5));
    uint2 ug = *(const uint2*)(Xc + ((size_t)i6 << 5));
    uint2 uh = *(const uint2*)(Xc + ((size_t)i7 << 5));
    a0 += __builtin_amdgcn_cvt_pk_f32_fp8(ua.x, false);
    a1 += __builtin_amdgcn_cvt_pk_f32_fp8(ua.x, true);
    a2 += __builtin_amdgcn_cvt_pk_f32_fp8(ua.y, false);
    a3 += __builtin_amdgcn_cvt_pk_f32_fp8(ua.y, true);
    a0 += __builtin_amdgcn_cvt_pk_f32_fp8(ub.x, false);
    a1 += __builtin_amdgcn_cvt_pk_f32_fp8(ub.x, true);
    a2 += __builtin_amdgcn_cvt_pk_f32_fp8(ub.y, false);
    a3 += __builtin_amdgcn_cvt_pk_f32_fp8(ub.y, true);
    a0 += __builtin_amdgcn_cvt_pk_f32_fp8(uc.x, false);
    a1 += __builtin_amdgcn_cvt_pk_f32_fp8(uc.x, true);
    a2 += __builtin_amdgcn_cvt_pk_f32_fp8(uc.y, false);
    a3 += __builtin_amdgcn_cvt_pk_f32_fp8(uc.y, true);
    a0 += __builtin_amdgcn_cvt_pk_f32_fp8(ud.x, false);
    a1 += __builtin_amdgcn_cvt_pk_f32_fp8(ud.x, true);
    a2 += __builtin_amdgcn_cvt_pk_f32_fp8(ud.y, false);
    a3 += __builtin_amdgcn_cvt_pk_f32_fp8(ud.y, true);
    a0 += __builtin_amdgcn_cvt_pk_f32_fp8(ue.x, false);
    a1 += __builtin_amdgcn_cvt_pk_f32_fp8(ue.x, true);
    a2 += __builtin_amdgcn_cvt_pk_f32_fp8(ue.y, false);
    a3 += __builtin_amdgcn_cvt_pk_f32_fp8(ue.y, true);
    a0 += __builtin_amdgcn_cvt_pk_f32_fp8(uf.x, false);
    a1 += __builtin_amdgcn_cvt_pk_f32_fp8(uf.x, true);
    a2 += __builtin_amdgcn_cvt_pk_f32_fp8(uf.y, false);
    a3 += __builtin_amdgcn_cvt_pk_f32_fp8(uf.y, true);
    a0 += __builtin_amdgcn_cvt_pk_f32_fp8(ug.x, false);
    a1 += __builtin_amdgcn_cvt_pk_f32_fp8(ug.x, true);
    a2 += __builtin_amdgcn_cvt_pk_f32_fp8(ug.y, false);
    a3 += __builtin_amdgcn_cvt_pk_f32_fp8(ug.y, true);
    a0 += __builtin_amdgcn_cvt_pk_f32_fp8(uh.x, false);
    a1 += __builtin_amdgcn_cvt_pk_f32_fp8(uh.x, true);
    a2 += __builtin_amdgcn_cvt_pk_f32_fp8(uh.y, false);
    a3 += __builtin_amdgcn_cvt_pk_f32_fp8(uh.y, true);
  }
  if (e + 4 <= d) {
    int i0 = idxp[e];
    int i1 = idxp[e + 1];
    int i2 = idxp[e + 2];
    int i3 = idxp[e + 3];
    uint2 ua = *(const uint2*)(Xc + ((size_t)i0 << 5));
    uint2 ub = *(const uint2*)(Xc + ((size_t)i1 << 5));
    uint2 uc = *(const uint2*)(Xc + ((size_t)i2 << 5));
    uint2 ud = *(const uint2*)(Xc + ((size_t)i3 << 5));
    a0 += __builtin_amdgcn_cvt_pk_f32_fp8(ua.x, false);
    a1 += __builtin_amdgcn_cvt_pk_f32_fp8(ua.x, true);
    a2 += __builtin_amdgcn_cvt_pk_f32_fp8(ua.y, false);
    a3 += __builtin_amdgcn_cvt_pk_f32_fp8(ua.y, true);
    a0 += __builtin_amdgcn_cvt_pk_f32_fp8(ub.x, false);
    a1 += __builtin_amdgcn_cvt_pk_f32_fp8(ub.x, true);
    a2 += __builtin_amdgcn_cvt_pk_f32_fp8(ub.y, false);
    a3 += __builtin_amdgcn_cvt_pk_f32_fp8(ub.y, true);
    a0 += __builtin_amdgcn_cvt_pk_f32_fp8(uc.x, false);
    a1 += __builtin_amdgcn_cvt_pk_f32_fp8(uc.x, true);
    a2 += __builtin_amdgcn_cvt_pk_f32_fp8(uc.y, false);
    a3 += __builtin_amdgcn_cvt_pk_f32_fp8(uc.y, true);
    a0 += __builtin_amdgcn_cvt_pk_f32_fp8(ud.x, false);
    a1 += __builtin_amdgcn_cvt_pk_f32_fp8(ud.x, true);
    a2 += __builtin_amdgcn_cvt_pk_f32_fp8(ud.y, false);
    a3 += __builtin_amdgcn_cvt_pk_f32_fp8(ud.y, true);
    e += 4;
  }
  for (; e < d; ++e) {  // tail 0..3 edges
    int i0 = idxp[e];
    uint2 ua = *(const uint2*)(Xc + ((size_t)i0 << 5));
    a0 += __builtin_amdgcn_cvt_pk_f32_fp8(ua.x, false);
    a1 += __builtin_amdgcn_cvt_pk_f32_fp8(ua.x, true);
    a2 += __builtin_amdgcn_cvt_pk_f32_fp8(ua.y, false);
    a3 += __builtin_amdgcn_cvt_pk_f32_fp8(ua.y, true);
  }

  float scale = (d > 0) ? (1.0f / (float)d) : 0.0f;
  uint4 o;
  o.x = f2bf(a0.x * scale) | (f2bf(a0.y * scale) << 16);
  o.y = f2bf(a1.x * scale) | (f2bf(a1.y * scale) << 16);
  o.z = f2bf(a2.x * scale) | (f2bf(a2.y * scale) << 16);
  o.w = f2bf(a3.x * scale) | (f2bf(a3.y * scale) << 16);
  *(uint4*)&Ah[(size_t)v * 64 + lc * 4] = o;
}

// ---------------- MFMA GEMM: out = (x + A) @ Wt^T + bias ----------------
// 512 threads, 128-row tile. W staged ONCE in LDS (only LDS use); A-fragments built
// directly from global per lane. LAYER=1: x f32 X -> transpose epilogue via WS (reused),
// bf16 Hh + fp8 Hq, RELU. LAYER=2: x bf16 Hh -> direct f32 stores.

template <int LAYER>
__global__ __launch_bounds__(512) void gemm_mfma(const float* __restrict__ Xf,
                                                 const uint32_t* __restrict__ Xb,
                                                 const uint32_t* __restrict__ Ab,
                                                 const uint32_t* __restrict__ Wt,
                                                 const float* __restrict__ bias,
                                                 float* __restrict__ outF,
                                                 uint32_t* __restrict__ outH,
                                                 uint8_t* __restrict__ outQ, int N) {
  __shared__ short WS[128 * GP];
  int t = threadIdx.x;
  int vbase = blockIdx.x * 128;

  // stage Wt (16B chunks): 2048 chunks of 8 shorts
  for (int c = t; c < 2048; c += 512) {
    int row = c >> 4, col8 = (c & 15) * 8;
    uint4 w = *(const uint4*)&Wt[row * 64 + (col8 >> 1)];
    *(uint4*)&WS[row * GP + col8] = w;
  }

  int wave = t >> 6, l = t & 63;
  int wr = wave * 16;                    // wave's 16 output rows (0..127)
  int lr = l & 15, hi = l >> 4;
  int grow = vbase + wr + lr;            // global row whose A-fragment this lane holds
  int arow = (grow < N) ? grow : (N - 1);  // clamp: garbage only corrupts OOB rows

  // build A-fragments for all 4 ks directly from global (8 loads in flight)
  uint4 af[4];
  if (LAYER == 1) {
#pragma unroll
    for (int ks = 0; ks < 4; ++ks) {
      int k0 = ks * 32 + hi * 8;
      float4 x0 = *(const float4*)&Xf[(size_t)arow * FEATS + k0];
      float4 x1 = *(const float4*)&Xf[(size_t)arow * FEATS + k0 + 4];
      uint4 au = *(const uint4*)&Ab[(size_t)arow * 64 + (k0 >> 1)];
      af[ks].x = f2bf(x0.x + bflo(au.x)) | (f2bf(x0.y + bfhi(au.x)) << 16);
      af[ks].y = f2bf(x0.z + bflo(au.y)) | (f2bf(x0.w + bfhi(au.y)) << 16);
      af[ks].z = f2bf(x1.x + bflo(au.z)) | (f2bf(x1.y + bfhi(au.z)) << 16);
      af[ks].w = f2bf(x1.z + bflo(au.w)) | (f2bf(x1.w + bfhi(au.w)) << 16);
    }
  } else {
#pragma unroll
    for (int ks = 0; ks < 4; ++ks) {
      int k0 = ks * 32 + hi * 8;
      uint4 xu = *(const uint4*)&Xb[(size_t)arow * 64 + (k0 >> 1)];
      uint4 au = *(const uint4*)&Ab[(size_t)arow * 64 + (k0 >> 1)];
      af[ks].x = f2bf(bflo(xu.x) + bflo(au.x)) | (f2bf(bfhi(xu.x) + bfhi(au.x)) << 16);
      af[ks].y = f2bf(bflo(xu.y) + bflo(au.y)) | (f2bf(bfhi(xu.y) + bfhi(au.y)) << 16);
      af[ks].z = f2bf(bflo(xu.z) + bflo(au.z)) | (f2bf(bfhi(xu.z) + bfhi(au.z)) << 16);
      af[ks].w = f2bf(bflo(xu.w) + bflo(au.w)) | (f2bf(bfhi(xu.w) + bfhi(au.w)) << 16);
    }
  }
  __syncthreads();  // WS ready

  f32x4 acc[8];
#pragma unroll
  for (int i = 0; i < 8; ++i) acc[i] = (f32x4){0.f, 0.f, 0.f, 0.f};

#pragma unroll
  for (int ks = 0; ks < 4; ++ks) {
    bf16x8 a = *(const bf16x8*)&af[ks];
    int k0 = ks * 32 + hi * 8;
#pragma unroll
    for (int nf = 0; nf < 8; ++nf) {
      bf16x8 b = *(const bf16x8*)&WS[(nf * 16 + lr) * GP + k0];
      acc[nf] = __builtin_amdgcn_mfma_f32_16x16x32_bf16(a, b, acc[nf], 0, 0, 0);
    }
  }

  // epilogue: D col = lane&15, row = hi*4 + j (within wave's 16 rows)
  int orow = wr + hi * 4;
  if (LAYER == 1) {
    __syncthreads();  // W consumed; reuse WS for output transpose (128 x GP shorts)
#pragma unroll
    for (int nf = 0; nf < 8; ++nf) {
      int col = nf * 16 + lr;
      float bv = bias[col];
#pragma unroll
      for (int j = 0; j < 4; ++j) {
        float o = fmaxf(acc[nf][j] + bv, 0.f);
        ((uint16_t*)WS)[(orow + j) * GP + col] = (uint16_t)f2bf(o);
      }
    }
    __syncthreads();
    // coalesced write-out: 128 rows x 128 bf16 -> Hh (uint4) + fp8 -> Hq (uint2)
    for (int i = t; i < 2048; i += 512) {
      int row = i >> 4, c8 = (i & 15) * 8;
      int v = vbase + row;
      if (v < N) {
        uint4 hv = *(const uint4*)&WS[row * GP + c8];
        *(uint4*)((uint16_t*)outH + (size_t)v * FEATS + c8) = hv;
        uint32_t q0 = __builtin_amdgcn_cvt_pk_fp8_f32(bflo(hv.x), bfhi(hv.x), 0, false);
        q0 = __builtin_amdgcn_cvt_pk_fp8_f32(bflo(hv.y), bfhi(hv.y), q0, true);
        uint32_t q1 = __builtin_amdgcn_cvt_pk_fp8_f32(bflo(hv.z), bfhi(hv.z), 0, false);
        q1 = __builtin_amdgcn_cvt_pk_fp8_f32(bflo(hv.w), bfhi(hv.w), q1, true);
        *(uint2*)(outQ + (size_t)v * FEATS + c8) = make_uint2(q0, q1);
      }
    }
  } else {
#pragma unroll
    for (int nf = 0; nf < 8; ++nf) {
      int col = nf * 16 + lr;
      float bv = bias[col];
#pragma unroll
      for (int j = 0; j < 4; ++j) {
        int v = vbase + orow + j;
        if (v < N) outF[(size_t)v * FEATS + col] = acc[nf][j] + bv;
      }
    }
  }
}

// ---------------- launcher ----------------

extern "C" void kernel_launch(void* const* d_in, const int* in_sizes, int n_in,
                              void* d_out, int out_size, void* d_ws, size_t ws_size,
                              hipStream_t stream) {
  const float* X = (const float*)d_in[0];
  const int* src = (const int*)d_in[1];
  const int* dst = (const int*)d_in[2];
  const float* W1 = (const float*)d_in[3];
  const float* b1 = (const float*)d_in[4];
  const float* W2 = (const float*)d_in[5];
  const float* b2 = (const float*)d_in[6];
  float* out = (float*)d_out;

  int N = in_sizes[0] / FEATS;
  int E = in_sizes[1];
  int NB = (N + 255) / 256;  // dst-page buckets

  char* ws = (char*)d_ws;
  auto alloc = [&](size_t bytes) -> char* {
    char* p = ws;
    ws += (bytes + 255) & ~(size_t)255;
    return p;
  };
  int2* offdeg = (int2*)alloc((size_t)N * 8);
  int* blockHist = (int*)alloc((size_t)CH_BLOCKS * NB_MAX * 4);  // per-block hists (no memset needed)
  int* bucketBase = (int*)alloc((size_t)(NB_MAX + 1) * 4);
  int* bucketCursor = (int*)alloc((size_t)NB_MAX * 4);
  uint32_t* pairs = (uint32_t*)alloc((size_t)E * 4);
  int* srcSorted = (int*)alloc((size_t)E * 4);
  uint32_t* Xq = (uint32_t*)alloc((size_t)N * 32 * 4);  // fp8 X; becomes fp8 h1 after gemm1 (alias)
  uint32_t* Ah = (uint32_t*)alloc((size_t)N * 64 * 4);  // bf16 aggregate
  uint32_t* Hh = (uint32_t*)alloc((size_t)N * 64 * 4);  // bf16 h1
  uint32_t* Wt1 = (uint32_t*)alloc((size_t)64 * 128 * 4);
  uint32_t* Wt2 = (uint32_t*)alloc((size_t)64 * 128 * 4);
  uint32_t* Hq = Xq;  // safe alias: Xq fully consumed by agg1 before gemm1 writes Hq

  // ---- fused fp8 cast + per-block bucket histogram + W transpose (no memset in graph) ----
  int nq = N * 32;
  cast_hist_kernel<<<CH_BLOCKS + 2, 256, 0, stream>>>(X, Xq, nq, dst, blockHist, E,
                                                      W1, W2, Wt1, Wt2);

  // ---- CSR build (no global per-node atomics anywhere) ----
  bucket_scan_kernel<<<1, NB_MAX, 0, stream>>>(blockHist, bucketBase, bucketCursor, NB);
  pairscatter_kernel<<<(E + PS_CHUNK - 1) / PS_CHUNK, PS_B, 0, stream>>>(src, dst, bucketCursor,
                                                                         pairs, E);
  fused_final_kernel<<<NB, 256, 0, stream>>>(pairs, bucketBase, offdeg, srcSorted, N);

  int aggBlocks = (N + 15) / 16;
  int gb = (N + 127) / 128;

  // ---- layer 1: Ah = agg_fp8(Xq); Hh/Hq = relu((X+Ah)@W1+b1) ----
  agg_kernel<<<aggBlocks, 256, 0, stream>>>(Xq, srcSorted, offdeg, Ah, N);
  gemm_mfma<1><<<gb, 512, 0, stream>>>(X, nullptr, Ah, Wt1, b1, nullptr, Hh, (uint8_t*)Hq, N);

  // ---- layer 2: Ah = agg_fp8(Hq); out = (Hh+Ah)@W2+b2 (f32) ----
  agg_kernel<<<aggBlocks, 256, 0, stream>>>(Hq, srcSorted, offdeg, Ah, N);
  gemm_mfma<2><<<gb, 512, 0, stream>>>(nullptr, Hh, Ah, Wt2, b2, out, nullptr, nullptr, N);
}